// Round 3
// baseline (340.513 us; speedup 1.0000x reference)
//
#include <hip/hip_runtime.h>
#include <hip/hip_cooperative_groups.h>

namespace cg = cooperative_groups;

// Chamfer distance, pred/target: (4, 8192, 3) fp32.
// Single cooperative kernel: init | fused-pairs | reduce, separated by
// grid.sync(). Dot-product form with deferred per-row |p|^2 (3 fma + 1 min
// per pair for the row direction). Clamp-to-0 commutes with min, applied at
// row finalization / final read, which also makes int atomicMin safe for
// slightly-negative dot-form results.

#define NPTS   8192
#define BATCH  4
#define RPT    4
#define BLOCK  256
#define PTILE  (RPT * BLOCK)              // 1024 rows per block
#define NTILES (NPTS / PTILE)             // 8
#define CHUNK  256                        // cols per block
#define NCHUNK (NPTS / CHUNK)             // 32
#define NBLK   (NTILES * NCHUNK * BATCH)  // 1024 blocks
#define NMINS  (2 * BATCH * NPTS)         // 65536 = NBLK * 64

__global__ __launch_bounds__(BLOCK, 4) void chamfer_coop(
    const float* __restrict__ pred, const float* __restrict__ target,
    int* __restrict__ mins, float* __restrict__ partials,
    float* __restrict__ out)
{
    __shared__ float4 q4[CHUNK];     // {qx, qy, qz, |q|^2}
    __shared__ int    cmin_s[CHUNK]; // per-block column mins (int bits)
    __shared__ float  ps[4];

    cg::grid_group grid = cg::this_grid();
    const int tid = threadIdx.x;
    const int bid = blockIdx.x;

    // ---- phase 0: init global min array (64 entries per block) ----
    if (tid < 64) mins[bid * 64 + tid] = 0x7F7F7F7F;  // 3.39e38f
    grid.sync();

    // ---- phase 1: fused pairwise mins ----
    const int b     = bid >> 8;         // 4 batches
    const int tile  = (bid >> 5) & 7;   // 8 i-tiles
    const int chunk = bid & 31;         // 32 j-chunks

    const float* __restrict__ P = pred   + b * NPTS * 3;
    const float* __restrict__ Q = target + b * NPTS * 3;
    const int i0 = tile * PTILE + tid;
    const int j0 = chunk * CHUNK;

    // stage target chunk: one float4 per point
    {
        const float* qp = Q + 3 * (j0 + tid);
        const float qx = qp[0], qy = qp[1], qz = qp[2];
        q4[tid] = make_float4(qx, qy, qz, fmaf(qx, qx, fmaf(qy, qy, qz * qz)));
        cmin_s[tid] = 0x7F7F7F7F;
    }
    __syncthreads();

    float pxn[RPT], pyn[RPT], pzn[RPT], p2[RPT], m[RPT];
#pragma unroll
    for (int r = 0; r < RPT; ++r) {
        const float* pp = P + 3 * (i0 + r * BLOCK);
        const float x = pp[0], y = pp[1], z = pp[2];
        pxn[r] = -2.0f * x;
        pyn[r] = -2.0f * y;
        pzn[r] = -2.0f * z;
        p2[r]  = fmaf(x, x, fmaf(y, y, z * z));
        m[r]   = 3.0e38f;
    }

#pragma unroll 2
    for (int jj = 0; jj < CHUNK; ++jj) {
        const int j = (tid + jj) & (CHUNK - 1);   // staggered: unique per lane
        const float4 q = q4[j];
        float d[RPT];
#pragma unroll
        for (int r = 0; r < RPT; ++r) {
            float t = fmaf(pxn[r], q.x, q.w);     // |q|^2 - 2 p.q  (partial)
            t = fmaf(pyn[r], q.y, t);
            t = fmaf(pzn[r], q.z, t);
            m[r] = fminf(m[r], t);                // row-min: defer +|p|^2
            d[r] = t + p2[r];                     // full d^2 for col-min
        }
        const float cm = fminf(fminf(d[0], d[1]), fminf(d[2], d[3]));
        atomicMin(&cmin_s[j], __float_as_int(cm));
    }

    int* __restrict__ fwd = mins + b * NPTS;
    int* __restrict__ bwd = mins + (BATCH + b) * NPTS;
#pragma unroll
    for (int r = 0; r < RPT; ++r) {
        const float v = fmaxf(m[r] + p2[r], 0.0f);   // clamp commutes with min
        atomicMin(&fwd[i0 + r * BLOCK], __float_as_int(v));
    }
    __syncthreads();
    atomicMin(&bwd[j0 + tid], cmin_s[tid]);

    grid.sync();

    // ---- phase 2a: each block reduces its 64-entry slice ----
    if (tid < 64) {
        float s = fmaxf(__int_as_float(mins[bid * 64 + tid]), 0.0f);
        for (int off = 32; off > 0; off >>= 1)
            s += __shfl_down(s, off, 64);
        if (tid == 0) partials[bid] = s;
    }
    grid.sync();

    // ---- phase 2b: block 0 folds 1024 partials ----
    if (bid == 0) {
        float t = partials[tid] + partials[tid + 256] +
                  partials[tid + 512] + partials[tid + 768];
        for (int off = 32; off > 0; off >>= 1)
            t += __shfl_down(t, off, 64);
        if ((tid & 63) == 0) ps[tid >> 6] = t;
        __syncthreads();
        if (tid == 0)
            out[0] = (ps[0] + ps[1] + ps[2] + ps[3]) * (1.0f / (BATCH * NPTS));
    }
}

extern "C" void kernel_launch(void* const* d_in, const int* in_sizes, int n_in,
                              void* d_out, int out_size, void* d_ws, size_t ws_size,
                              hipStream_t stream)
{
    const float* pred   = (const float*)d_in[0];
    const float* target = (const float*)d_in[1];
    float* out = (float*)d_out;
    int*   mins     = (int*)d_ws;                 // [2][BATCH][NPTS]
    float* partials = (float*)d_ws + NMINS;       // [NBLK]

    void* args[] = {(void*)&pred, (void*)&target, (void*)&mins,
                    (void*)&partials, (void*)&out};
    hipLaunchCooperativeKernel((const void*)chamfer_coop, dim3(NBLK), dim3(BLOCK),
                               args, 0, stream);
}

// Round 5
// 93.232 us; speedup vs baseline: 3.6523x; 3.6523x over previous
//
#include <hip/hip_runtime.h>

// Chamfer distance, pred/target: (4, 8192, 3) fp32.
// Round-2 proven multi-dispatch structure + dot-form inner loop.
// Each d2(i,j) evaluated once: row-min in registers with deferred |p|^2,
// col-min via LDS atomicMin at per-lane staggered j (unique j per lane
// within a wave -> no same-address serialization). Global combine via
// int atomicMin (d2 clamped >= 0 at read; negative dot-form results
// int-compare below all positives and clamp to 0, preserving the min).

#define NPTS   8192
#define BATCH  4
#define RPT    8                  // register-resident rows per thread
#define BLOCK  256
#define PTILE  (RPT * BLOCK)      // 2048 rows per block
#define NTILES (NPTS / PTILE)     // 4
#define CHUNK  128                // streamed cols per block
#define NCHUNK (NPTS / CHUNK)     // 64  -> grid 4*64*4 = 1024 blocks (4/CU)
#define NMINS  (2 * BATCH * NPTS) // 65536

__global__ __launch_bounds__(BLOCK, 1) void chamfer_pairs(
    const float* __restrict__ pred, const float* __restrict__ target,
    int* __restrict__ mins)
{
    __shared__ float4 q4[CHUNK];      // {qx, qy, qz, |q|^2}
    __shared__ int    cmin_s[CHUNK];  // per-block column mins (int bits)

    const int b = blockIdx.z;
    const float* __restrict__ P = pred   + b * NPTS * 3;
    const float* __restrict__ Q = target + b * NPTS * 3;

    const int tid = threadIdx.x;
    const int i0  = blockIdx.x * PTILE + tid;
    const int j0  = blockIdx.y * CHUNK;

    if (tid < CHUNK) {
        const float* qp = Q + 3 * (j0 + tid);
        const float qx = qp[0], qy = qp[1], qz = qp[2];
        q4[tid] = make_float4(qx, qy, qz, fmaf(qx, qx, fmaf(qy, qy, qz * qz)));
        cmin_s[tid] = 0x7F7F7F7F;   // 3.39e38f
    }
    __syncthreads();

    float pxn[RPT], pyn[RPT], pzn[RPT], p2[RPT], m[RPT];
#pragma unroll
    for (int r = 0; r < RPT; ++r) {
        const float* pp = P + 3 * (i0 + r * BLOCK);
        const float x = pp[0], y = pp[1], z = pp[2];
        pxn[r] = -2.0f * x;
        pyn[r] = -2.0f * y;
        pzn[r] = -2.0f * z;
        p2[r]  = fmaf(x, x, fmaf(y, y, z * z));
        m[r]   = 3.0e38f;
    }

#pragma unroll 2
    for (int jj = 0; jj < CHUNK; ++jj) {
        const int j = (tid + jj) & (CHUNK - 1);   // unique j per lane in a wave
        const float4 q = q4[j];                   // ds_read_b128
        float d[RPT];
#pragma unroll
        for (int r = 0; r < RPT; ++r) {
            float t = fmaf(pxn[r], q.x, q.w);     // |q|^2 - 2 p.q
            t = fmaf(pyn[r], q.y, t);
            t = fmaf(pzn[r], q.z, t);
            m[r] = fminf(m[r], t);                // row-min, |p|^2 deferred
            d[r] = t + p2[r];                     // full d^2 for col-min
        }
        // balanced tree (compiler can fuse pairs into v_min3_f32)
        const float cm = fminf(fminf(fminf(d[0], d[1]), fminf(d[2], d[3])),
                               fminf(fminf(d[4], d[5]), fminf(d[6], d[7])));
        atomicMin(&cmin_s[j], __float_as_int(cm));
    }

    int* __restrict__ fwd = mins + b * NPTS;
    int* __restrict__ bwd = mins + (BATCH + b) * NPTS;
#pragma unroll
    for (int r = 0; r < RPT; ++r) {
        const float v = fmaxf(m[r] + p2[r], 0.0f);   // clamp commutes with min
        atomicMin(&fwd[i0 + r * BLOCK], __float_as_int(v));
    }
    __syncthreads();
    if (tid < CHUNK)
        atomicMin(&bwd[j0 + tid], cmin_s[tid]);
}

__global__ __launch_bounds__(256) void chamfer_reduce1(
    const int* __restrict__ mins, float* __restrict__ partials)
{
    __shared__ float part[4];
    const int base = blockIdx.x * 1024 + threadIdx.x;

    float s = fmaxf(__int_as_float(mins[base]),       0.0f) +
              fmaxf(__int_as_float(mins[base + 256]), 0.0f) +
              fmaxf(__int_as_float(mins[base + 512]), 0.0f) +
              fmaxf(__int_as_float(mins[base + 768]), 0.0f);

    for (int off = 32; off > 0; off >>= 1)
        s += __shfl_down(s, off, 64);
    if ((threadIdx.x & 63) == 0)
        part[threadIdx.x >> 6] = s;
    __syncthreads();

    if (threadIdx.x == 0)
        partials[blockIdx.x] = part[0] + part[1] + part[2] + part[3];
}

__global__ __launch_bounds__(64) void chamfer_reduce2(
    const float* __restrict__ partials, float* __restrict__ out)
{
    float t = partials[threadIdx.x];
    for (int off = 32; off > 0; off >>= 1)
        t += __shfl_down(t, off, 64);
    if (threadIdx.x == 0)
        out[0] = t * (1.0f / (float)(BATCH * NPTS));  // /32768
}

extern "C" void kernel_launch(void* const* d_in, const int* in_sizes, int n_in,
                              void* d_out, int out_size, void* d_ws, size_t ws_size,
                              hipStream_t stream)
{
    const float* pred   = (const float*)d_in[0];
    const float* target = (const float*)d_in[1];
    float* out = (float*)d_out;
    int*   mins     = (int*)d_ws;             // [2][BATCH][NPTS]
    float* partials = (float*)d_ws + NMINS;   // [64]

    hipMemsetAsync(mins, 0x7F, (size_t)NMINS * sizeof(int), stream);

    dim3 grid(NTILES, NCHUNK, BATCH);
    chamfer_pairs<<<grid, BLOCK, 0, stream>>>(pred, target, mins);
    chamfer_reduce1<<<64, 256, 0, stream>>>(mins, partials);
    chamfer_reduce2<<<1, 64, 0, stream>>>(partials, out);
}

// Round 10
// 90.206 us; speedup vs baseline: 3.7748x; 1.0335x over previous
//
#include <hip/hip_runtime.h>

// Chamfer distance, pred/target: (4, 8192, 3) fp32.
// Round-5 structure + packed-fp32 inner loop: two j-columns per iteration
// via v_pk_fma_f32 (float2 ext-vector + __builtin_elementwise_fma).
// LDS staged as SoA float2 pairs so ds_read_b64 delivers packed q
// components with no repacking. Row-min folds both halves with min3;
// col-min trees per half + LDS atomicMin at per-lane staggered pair index.

typedef float f32x2 __attribute__((ext_vector_type(2)));

#define NPTS   8192
#define BATCH  4
#define RPT    8                  // register-resident rows per thread
#define BLOCK  256
#define PTILE  (RPT * BLOCK)      // 2048 rows per block
#define NTILES (NPTS / PTILE)     // 4
#define CHUNK  128                // streamed cols per block
#define NPAIR  (CHUNK / 2)        // 64 column pairs
#define NCHUNK (NPTS / CHUNK)     // 64  -> grid 4*64*4 = 1024 blocks (4/CU)
#define NMINS  (2 * BATCH * NPTS) // 65536

__global__ __launch_bounds__(BLOCK, 4) void chamfer_pairs(
    const float* __restrict__ pred, const float* __restrict__ target,
    int* __restrict__ mins)
{
    __shared__ f32x2 qx2[NPAIR], qy2[NPAIR], qz2[NPAIR], qw2[NPAIR];
    __shared__ int   cmin_s[CHUNK];   // per-block column mins (int bits)

    const int b = blockIdx.z;
    const float* __restrict__ P = pred   + b * NPTS * 3;
    const float* __restrict__ Q = target + b * NPTS * 3;

    const int tid = threadIdx.x;
    const int i0  = blockIdx.x * PTILE + tid;
    const int j0  = blockIdx.y * CHUNK;

    if (tid < CHUNK) {
        const float* qp = Q + 3 * (j0 + tid);
        const float qx = qp[0], qy = qp[1], qz = qp[2];
        ((float*)qx2)[tid] = qx;
        ((float*)qy2)[tid] = qy;
        ((float*)qz2)[tid] = qz;
        ((float*)qw2)[tid] = fmaf(qx, qx, fmaf(qy, qy, qz * qz));
        cmin_s[tid] = 0x7F7F7F7F;   // 3.39e38f
    }
    __syncthreads();

    f32x2 pxn2[RPT], pyn2[RPT], pzn2[RPT], p22[RPT];
    float m[RPT];
#pragma unroll
    for (int r = 0; r < RPT; ++r) {
        const float* pp = P + 3 * (i0 + r * BLOCK);
        const float x = pp[0], y = pp[1], z = pp[2];
        const float nx = -2.0f * x, ny = -2.0f * y, nz = -2.0f * z;
        const float p2 = fmaf(x, x, fmaf(y, y, z * z));
        pxn2[r] = (f32x2){nx, nx};
        pyn2[r] = (f32x2){ny, ny};
        pzn2[r] = (f32x2){nz, nz};
        p22[r]  = (f32x2){p2, p2};
        m[r]    = 3.0e38f;
    }

    // per-lane staggered pair index, decorrelated across the 4 waves
    const int soff = (tid & 63) + ((tid >> 6) << 4);

#pragma unroll 2
    for (int jj = 0; jj < NPAIR; ++jj) {
        const int jp = (soff + jj) & (NPAIR - 1);
        const f32x2 qx = qx2[jp];      // ds_read_b64, packed {q[2jp],q[2jp+1]}
        const f32x2 qy = qy2[jp];
        const f32x2 qz = qz2[jp];
        const f32x2 qw = qw2[jp];

        f32x2 d[RPT];
#pragma unroll
        for (int r = 0; r < RPT; ++r) {
            f32x2 t = __builtin_elementwise_fma(pxn2[r], qx, qw);  // |q|^2 - 2p.q
            t = __builtin_elementwise_fma(pyn2[r], qy, t);
            t = __builtin_elementwise_fma(pzn2[r], qz, t);
            m[r] = fminf(fminf(m[r], t.x), t.y);   // v_min3, |p|^2 deferred
            d[r] = t + p22[r];                     // v_pk_add: full d^2 pair
        }
        // col-min trees per half, min3-friendly nesting
        const float cl = fminf(
            fminf(fminf(fminf(d[0].x, d[1].x), d[2].x),
                  fminf(fminf(d[3].x, d[4].x), d[5].x)),
            fminf(d[6].x, d[7].x));
        const float ch = fminf(
            fminf(fminf(fminf(d[0].y, d[1].y), d[2].y),
                  fminf(fminf(d[3].y, d[4].y), d[5].y)),
            fminf(d[6].y, d[7].y));
        atomicMin(&cmin_s[2 * jp],     __float_as_int(cl));
        atomicMin(&cmin_s[2 * jp + 1], __float_as_int(ch));
    }

    int* __restrict__ fwd = mins + b * NPTS;
    int* __restrict__ bwd = mins + (BATCH + b) * NPTS;
#pragma unroll
    for (int r = 0; r < RPT; ++r) {
        const float v = fmaxf(m[r] + p22[r].x, 0.0f);  // clamp commutes with min
        atomicMin(&fwd[i0 + r * BLOCK], __float_as_int(v));
    }
    __syncthreads();
    if (tid < CHUNK)
        atomicMin(&bwd[j0 + tid], cmin_s[tid]);
}

__global__ __launch_bounds__(256) void chamfer_reduce1(
    const int* __restrict__ mins, float* __restrict__ partials)
{
    __shared__ float part[4];
    const int base = blockIdx.x * 1024 + threadIdx.x;

    float s = fmaxf(__int_as_float(mins[base]),       0.0f) +
              fmaxf(__int_as_float(mins[base + 256]), 0.0f) +
              fmaxf(__int_as_float(mins[base + 512]), 0.0f) +
              fmaxf(__int_as_float(mins[base + 768]), 0.0f);

    for (int off = 32; off > 0; off >>= 1)
        s += __shfl_down(s, off, 64);
    if ((threadIdx.x & 63) == 0)
        part[threadIdx.x >> 6] = s;
    __syncthreads();

    if (threadIdx.x == 0)
        partials[blockIdx.x] = part[0] + part[1] + part[2] + part[3];
}

__global__ __launch_bounds__(64) void chamfer_reduce2(
    const float* __restrict__ partials, float* __restrict__ out)
{
    float t = partials[threadIdx.x];
    for (int off = 32; off > 0; off >>= 1)
        t += __shfl_down(t, off, 64);
    if (threadIdx.x == 0)
        out[0] = t * (1.0f / (float)(BATCH * NPTS));  // /32768
}

extern "C" void kernel_launch(void* const* d_in, const int* in_sizes, int n_in,
                              void* d_out, int out_size, void* d_ws, size_t ws_size,
                              hipStream_t stream)
{
    const float* pred   = (const float*)d_in[0];
    const float* target = (const float*)d_in[1];
    float* out = (float*)d_out;
    int*   mins     = (int*)d_ws;             // [2][BATCH][NPTS]
    float* partials = (float*)d_ws + NMINS;   // [64]

    hipMemsetAsync(mins, 0x7F, (size_t)NMINS * sizeof(int), stream);

    dim3 grid(NTILES, NCHUNK, BATCH);
    chamfer_pairs<<<grid, BLOCK, 0, stream>>>(pred, target, mins);
    chamfer_reduce1<<<64, 256, 0, stream>>>(mins, partials);
    chamfer_reduce2<<<1, 64, 0, stream>>>(partials, out);
}